// Round 9
// baseline (205.838 us; speedup 1.0000x reference)
//
#include <hip/hip_runtime.h>

#define NN 100000
#define NE 400000
#define F_IN 16
#define F_EDGE 8
#define EMB 16
#define NUM_GRAPHS 256

#define EDGE_GRID 2048
#define NTILES (NE / 64)            // 6250 64-edge tiles

#define NPB 128
#define NODE_BLOCKS ((NN + NPB - 1) / NPB)   // 782

#define SCAN_BD 1024
#define NSB ((NN + SCAN_BD - 1) / SCAN_BD)   // 98

// ---------------------------------------------------------------------------
// Workspace (4B units):
//   deg    [NN]     int  (zeroed)  in-degree histogram
//   rowptr [NN]     int            exclusive scan of deg (node start offsets)
//   wptr   [NN]     int            running fill pointers (init = rowptr)
//   bsum   [128]    int            scan block sums
//   gmax   [G*16]   u32 (zeroed)   pooled max (float bits; h>=0)
//   gsum   [G*16]   f32 (zeroed)
//   gcnt   [G]      f32 (zeroed)
//   msg    [NE*16]  f32            per-edge messages in CSR order (25.6 MB)
// ---------------------------------------------------------------------------
#define DEG_F4  (NN / 4)                                    // 25000
#define POOL_F4 ((2 * NUM_GRAPHS * EMB + NUM_GRAPHS) / 4)   // 2112
#define ZERO_F4 (DEG_F4 + POOL_F4)

__global__ __launch_bounds__(256) void zero_kernel(float4* __restrict__ deg4,
                                                   float4* __restrict__ pool4)
{
    const int i = blockIdx.x * 256 + threadIdx.x;
    const float4 z = make_float4(0.f, 0.f, 0.f, 0.f);
    if (i < DEG_F4) deg4[i] = z;
    else if (i < ZERO_F4) pool4[i - DEG_F4] = z;
}

__global__ __launch_bounds__(256) void hist_kernel(const int* __restrict__ ei,
                                                   int* __restrict__ deg)
{
    const int e = blockIdx.x * 256 + threadIdx.x;
    if (e < NE) atomicAdd(&deg[ei[NE + e]], 1);
}

__global__ __launch_bounds__(SCAN_BD) void scan_blocks(const int* __restrict__ deg,
                                                       int* __restrict__ rowptr,
                                                       int* __restrict__ bsum)
{
    __shared__ int sh[SCAN_BD];
    const int t = threadIdx.x;
    const int i = blockIdx.x * SCAN_BD + t;
    const int v = (i < NN) ? deg[i] : 0;
    sh[t] = v;
    __syncthreads();
    #pragma unroll
    for (int off = 1; off < SCAN_BD; off <<= 1) {
        const int add = (t >= off) ? sh[t - off] : 0;
        __syncthreads();
        sh[t] += add;
        __syncthreads();
    }
    if (i < NN) rowptr[i] = sh[t] - v;           // exclusive
    if (t == SCAN_BD - 1) bsum[blockIdx.x] = sh[t];
}

__global__ __launch_bounds__(128) void scan_tops(int* __restrict__ bsum)
{
    __shared__ int sb[128];
    const int t = threadIdx.x;
    const int v = (t < NSB) ? bsum[t] : 0;
    sb[t] = v;
    __syncthreads();
    #pragma unroll
    for (int off = 1; off < 128; off <<= 1) {
        const int add = (t >= off) ? sb[t - off] : 0;
        __syncthreads();
        sb[t] += add;
        __syncthreads();
    }
    if (t < NSB) bsum[t] = sb[t] - v;            // exclusive
}

__global__ __launch_bounds__(SCAN_BD) void scan_add(int* __restrict__ rowptr,
                                                    int* __restrict__ wptr,
                                                    const int* __restrict__ bsum)
{
    const int i = blockIdx.x * SCAN_BD + threadIdx.x;
    if (i < NN) {
        const int r = rowptr[i] + bsum[blockIdx.x];
        rowptr[i] = r;
        wptr[i]   = r;
    }
}

// ---------------------------------------------------------------------------
// Edge kernel — R8 MLP body (LDS weights stride-12, 4 edges/thread), but the
// epilogue is ONE atomic per edge (CSR slot claim by the o==0 lane, shfl-
// broadcast) + plain 64B-contiguous stores of the 16-channel message.
// ---------------------------------------------------------------------------
__global__ __launch_bounds__(256) void edge_kernel(
    const float* __restrict__ x, const int* __restrict__ ei,
    const float* __restrict__ ea, const float* __restrict__ nn1_w,
    const float* __restrict__ nn1_b, int* __restrict__ wptr,
    float* __restrict__ msg)
{
    __shared__ float wtp[256 * 12];   // row r=(i*16+o): 8 weights + bias + 3 pad

    const int tid = threadIdx.x;
    const int eL  = tid >> 4;
    const int o   = tid & 15;

    #pragma unroll
    for (int t = tid; t < F_IN * EMB * F_EDGE; t += 256)
        wtp[(t >> 3) * 12 + (t & 7)] = nn1_w[t];
    wtp[tid * 12 + 8] = nn1_b[tid];                    // row tid = i*16+o
    __syncthreads();                                   // the ONLY barrier

    float br[F_IN];
    #pragma unroll
    for (int i = 0; i < F_IN; i++) br[i] = wtp[(i * 16 + o) * 12 + 8];

    for (int t = blockIdx.x; t < NTILES; t += EDGE_GRID) {
        const int e0 = t * 64 + eL * 4;       // thread's 4 contiguous edges

        const int4 s4 = *(const int4*)&ei[e0];
        const int4 d4 = *(const int4*)&ei[NE + e0];
        const int src[4] = {s4.x, s4.y, s4.z, s4.w};
        const int dst[4] = {d4.x, d4.y, d4.z, d4.w};

        float4 A[8];                          // 4 edges x 8 attrs, contiguous
        #pragma unroll
        for (int r = 0; r < 8; r++) A[r] = *(const float4*)&ea[e0 * 8 + 4 * r];

        float acc[4] = {0.f, 0.f, 0.f, 0.f};

        #pragma unroll
        for (int h = 0; h < 2; h++) {         // halves of the i-dimension
            float4 xa[4], xb[4];
            #pragma unroll
            for (int e = 0; e < 4; e++) {
                xa[e] = *(const float4*)&x[src[e] * 16 + h * 8];
                xb[e] = *(const float4*)&x[src[e] * 16 + h * 8 + 4];
            }
            #pragma unroll
            for (int ii = 0; ii < 8; ii++) {
                const int i = h * 8 + ii;
                const float* wr = &wtp[(i * 16 + o) * 12];
                const float4 w0 = *(const float4*)wr;
                const float4 w1 = *(const float4*)(wr + 4);
                #pragma unroll
                for (int e = 0; e < 4; e++) {
                    const float4 a0 = A[2 * e];
                    const float4 a1 = A[2 * e + 1];
                    float u = br[i];
                    u = fmaf(a0.x, w0.x, u); u = fmaf(a0.y, w0.y, u);
                    u = fmaf(a0.z, w0.z, u); u = fmaf(a0.w, w0.w, u);
                    u = fmaf(a1.x, w1.x, u); u = fmaf(a1.y, w1.y, u);
                    u = fmaf(a1.z, w1.z, u); u = fmaf(a1.w, w1.w, u);
                    const float xv = (ii < 4)
                        ? ((ii == 0) ? xa[e].x : (ii == 1) ? xa[e].y
                                     : (ii == 2) ? xa[e].z : xa[e].w)
                        : ((ii == 4) ? xb[e].x : (ii == 5) ? xb[e].y
                                     : (ii == 6) ? xb[e].z : xb[e].w);
                    acc[e] = fmaf(xv, fmaxf(u, 0.f), acc[e]);
                }
            }
        }

        int p[4] = {0, 0, 0, 0};
        if (o == 0) {                          // one slot-claim atomic per edge
            #pragma unroll
            for (int e = 0; e < 4; e++) p[e] = atomicAdd(&wptr[dst[e]], 1);
        }
        const int lb = tid & 48;               // o-group base lane in wave
        #pragma unroll
        for (int e = 0; e < 4; e++) p[e] = __shfl(p[e], lb);
        #pragma unroll
        for (int e = 0; e < 4; e++)            // 16 lanes -> contiguous 64B
            msg[p[e] * 16 + o] = acc[e];
    }
}

// ---------------------------------------------------------------------------
// Node kernel: segmented sum of contiguous msg rows (no atomics, no eid
// indirection) + root transform + ReLU + register-segmented pooled flush.
// ---------------------------------------------------------------------------
__global__ __launch_bounds__(256) void node_kernel(
    const float* __restrict__ x, const int* __restrict__ batch,
    const float* __restrict__ root_w, const float* __restrict__ conv_b,
    const int* __restrict__ rowptr, const int* __restrict__ deg,
    const float* __restrict__ msg,
    unsigned int* __restrict__ gmax, float* __restrict__ gsum,
    float* __restrict__ gcnt)
{
    __shared__ float rwT[256];   // rwT[i*16+o] = root_w[o*16+i]
    __shared__ float xsh[256];
    __shared__ int   bsh[16];
    __shared__ float hsh[256];

    const int tid = threadIdx.x;
    const int j   = tid >> 4;
    const int o   = tid & 15;
    const int n0  = blockIdx.x * NPB;

    rwT[(tid & 15) * 16 + (tid >> 4)] = root_w[tid];
    const float cb = conv_b[o];

    int   curg = batch[n0];
    float am = 0.f, asum = 0.f, ac = 0.f;

    for (int s0 = 0; s0 < NPB; s0 += 16) {
        const int base = n0 + s0;
        const int idx  = base * 16 + tid;
        const float xv = (idx < NN * 16) ? x[idx] : 0.f;
        const int n = base + j;
        int st = 0, dg = 0;
        if (n < NN) { st = rowptr[n]; dg = deg[n]; }
        int bv = -1;
        if (tid < 16 && base + tid < NN) bv = batch[base + tid];

        __syncthreads();   // prev sub-tile's hsh/bsh fully consumed
        xsh[tid] = xv;
        if (tid < 16) bsh[tid] = bv;
        __syncthreads();

        float s = 0.f;
        for (int k = 0; k < dg; k++) s += msg[(st + k) * 16 + o];

        float a = cb + s / fmaxf((float)dg, 1.f);
        #pragma unroll
        for (int i = 0; i < F_IN; i++)
            a = fmaf(xsh[j * 16 + i], rwT[i * 16 + o], a);
        hsh[tid] = fmaxf(a, 0.f);
        __syncthreads();   // hsh ready

        if (tid < 16) {
            #pragma unroll 1
            for (int jj = 0; jj < 16; jj++) {
                const int g = bsh[jj];
                if (g < 0) break;
                if (g != curg) {
                    atomicMax(&gmax[curg * 16 + o], __float_as_uint(am));
                    atomicAdd(&gsum[curg * 16 + o], asum);
                    if (o == 0) atomicAdd(&gcnt[curg], ac);
                    am = 0.f; asum = 0.f; ac = 0.f; curg = g;
                }
                const float h = hsh[jj * 16 + o];
                am = fmaxf(am, h); asum += h; ac += 1.f;
            }
        }
    }

    if (tid < 16) {
        atomicMax(&gmax[curg * 16 + o], __float_as_uint(am));
        atomicAdd(&gsum[curg * 16 + o], asum);
        if (o == 0) atomicAdd(&gcnt[curg], ac);
    }
}

// Head MLP: one thread per graph, single block.
__global__ __launch_bounds__(256) void head_kernel(
    const unsigned int* __restrict__ gmax, const float* __restrict__ gsum,
    const float* __restrict__ gcnt,
    const float* __restrict__ lin1_w, const float* __restrict__ lin1_b,
    const float* __restrict__ lin2_w, const float* __restrict__ lin2_b,
    float* __restrict__ out)
{
    const int g = threadIdx.x;

    float pooled[2 * EMB];
    #pragma unroll
    for (int o = 0; o < EMB; o++) pooled[o] = __uint_as_float(gmax[g * 16 + o]);
    const float c = fmaxf(gcnt[g], 1.f);
    #pragma unroll
    for (int o = 0; o < EMB; o++) pooled[EMB + o] = gsum[g * 16 + o] / c;

    float acc = lin2_b[0];
    #pragma unroll
    for (int k = 0; k < EMB; k++) {
        float a = lin1_b[k];
        #pragma unroll
        for (int cc = 0; cc < 2 * EMB; cc++)
            a = fmaf(pooled[cc], lin1_w[k * 32 + cc], a);
        acc = fmaf(fmaxf(a, 0.f), lin2_w[k], acc);
    }
    out[g] = acc;
}

extern "C" void kernel_launch(void* const* d_in, const int* in_sizes, int n_in,
                              void* d_out, int out_size, void* d_ws, size_t ws_size,
                              hipStream_t stream) {
    const float* x      = (const float*)d_in[0];
    const int*   ei     = (const int*)d_in[1];
    const float* ea     = (const float*)d_in[2];
    const int*   batch  = (const int*)d_in[3];
    const float* nn1_w  = (const float*)d_in[4];
    const float* nn1_b  = (const float*)d_in[5];
    const float* root_w = (const float*)d_in[6];
    const float* conv_b = (const float*)d_in[7];
    const float* lin1_w = (const float*)d_in[8];
    const float* lin1_b = (const float*)d_in[9];
    const float* lin2_w = (const float*)d_in[10];
    const float* lin2_b = (const float*)d_in[11];
    float* out = (float*)d_out;

    int*          deg    = (int*)d_ws;
    int*          rowptr = deg + NN;
    int*          wptr   = rowptr + NN;
    int*          bsum   = wptr + NN;
    unsigned int* gmax   = (unsigned int*)(bsum + 128);
    float*        gsum   = (float*)(gmax + NUM_GRAPHS * EMB);
    float*        gcnt   = gsum + NUM_GRAPHS * EMB;
    float*        msg    = gcnt + NUM_GRAPHS;          // 25.6 MB

    zero_kernel<<<(ZERO_F4 + 255) / 256, 256, 0, stream>>>(
        (float4*)deg, (float4*)gmax);
    hist_kernel<<<(NE + 255) / 256, 256, 0, stream>>>(ei, deg);
    scan_blocks<<<NSB, SCAN_BD, 0, stream>>>(deg, rowptr, bsum);
    scan_tops<<<1, 128, 0, stream>>>(bsum);
    scan_add<<<NSB, SCAN_BD, 0, stream>>>(rowptr, wptr, bsum);
    edge_kernel<<<EDGE_GRID, 256, 0, stream>>>(x, ei, ea, nn1_w, nn1_b, wptr, msg);
    node_kernel<<<NODE_BLOCKS, 256, 0, stream>>>(
        x, batch, root_w, conv_b, rowptr, deg, msg, gmax, gsum, gcnt);
    head_kernel<<<1, 256, 0, stream>>>(gmax, gsum, gcnt,
                                       lin1_w, lin1_b, lin2_w, lin2_b, out);
}